// Round 11
// baseline (355.497 us; speedup 1.0000x reference)
//
#include <hip/hip_runtime.h>

#define SEQ 2048
#define HID 1024
#define NHEAD 16
#define HDIM 64
#define NB 4
#define NTOK (NB * SEQ)   // 8192
#define NQKV (3 * HID)    // 3072
#define LOG2E 1.44269504088896f
#define QSCALE (0.125f * LOG2E)   // folded into gemm0's Q-column epilogue

typedef __attribute__((ext_vector_type(8))) short bf16x8;
typedef __attribute__((ext_vector_type(4))) float f32x4;

// ---------- helpers ----------

__device__ __forceinline__ void glds16(const void* g, void* l) {
  // async global->LDS, 16B per lane; LDS dest = wave-uniform base + lane*16
  __builtin_amdgcn_global_load_lds(
      (const __attribute__((address_space(1))) void*)g,
      (__attribute__((address_space(3))) void*)l, 16, 0, 0);
}

__device__ __forceinline__ ushort f2bf(float f) {
  union { float f; unsigned int u; } a; a.f = f;
  unsigned int u = a.u;
  return (ushort)((u + 0x7fffu + ((u >> 16) & 1u)) >> 16);  // RNE
}

// pack two fp32 -> bf16x2 in ONE VALU op (RNE). T12 primitive; validated R1/R2.
__device__ __forceinline__ unsigned int cvtpk(float a, float b) {
  unsigned int r;
  asm("v_cvt_pk_bf16_f32 %0, %1, %2" : "=v"(r) : "v"(a), "v"(b));
  return r;  // lo = bf16(a), hi = bf16(b)
}

// ---------- 1. fused LayerNorm + weight-transpose + mask prescale ----------

__global__ __launch_bounds__(256) void ln_tr_fused(const float* __restrict__ x,
                                                   const float* __restrict__ g,
                                                   const float* __restrict__ be,
                                                   ushort* __restrict__ y,
                                                   const float* __restrict__ W0,
                                                   ushort* __restrict__ T0,
                                                   const float* __restrict__ W1,
                                                   ushort* __restrict__ T1,
                                                   const float* __restrict__ mask,
                                                   float* __restrict__ m2) {
  __shared__ float t[32][33];
  const int tid = threadIdx.x;
  if (blockIdx.x < NTOK) {
    const int row = blockIdx.x;
    const float4 v = ((const float4*)(x + (size_t)row * HID))[tid];
    float s  = v.x + v.y + v.z + v.w;
    float sq = v.x * v.x + v.y * v.y + v.z * v.z + v.w * v.w;
    for (int o = 1; o < 64; o <<= 1) { s += __shfl_xor(s, o, 64); sq += __shfl_xor(sq, o, 64); }
    const int wv = tid >> 6;
    if ((tid & 63) == 0) { t[0][wv] = s; t[1][wv] = sq; }
    __syncthreads();
    s  = t[0][0] + t[0][1] + t[0][2] + t[0][3];
    sq = t[1][0] + t[1][1] + t[1][2] + t[1][3];
    const float mu  = s * (1.0f / HID);
    const float var = sq * (1.0f / HID) - mu * mu;
    const float rs  = rsqrtf(var + 1e-12f);
    const float4 gv = ((const float4*)g)[tid];
    const float4 bv = ((const float4*)be)[tid];
    ushort4 o;
    o.x = f2bf((v.x - mu) * rs * gv.x + bv.x);
    o.y = f2bf((v.y - mu) * rs * gv.y + bv.y);
    o.z = f2bf((v.z - mu) * rs * gv.z + bv.z);
    o.w = f2bf((v.w - mu) * rs * gv.w + bv.w);
    ((ushort4*)(y + (size_t)row * HID))[tid] = o;
    return;
  }
  const int bid = blockIdx.x - NTOK;   // 0..4103
  if (bid >= 4096) {
    // mask prescale: 8 blocks x 1024 floats = NB*SEQ
    const int i = (bid - 4096) * 1024 + tid * 4;
    float4 v = *(const float4*)(mask + i);
    v.x *= LOG2E; v.y *= LOG2E; v.z *= LOG2E; v.w *= LOG2E;
    *(float4*)(m2 + i) = v;
    return;
  }
  // ---- transpose part ----
  const float* W; ushort* WT; int C, bx, by;
  if (bid < 3072) { W = W0; WT = T0; C = NQKV; bx = bid % 96; by = bid / 96; }
  else { const int b2 = bid - 3072; W = W1; WT = T1; C = HID; bx = b2 & 31; by = b2 >> 5; }
  const int R = HID;
  const int c0 = bx * 32, r0 = by * 32;
  const int tx = tid & 31, ty = tid >> 5;
  for (int j = 0; j < 4; ++j)
    t[ty + j * 8][tx] = W[(size_t)(r0 + ty + j * 8) * C + c0 + tx];
  __syncthreads();
  for (int j = 0; j < 4; ++j)
    WT[(size_t)(c0 + ty + j * 8) * R + r0 + tx] = f2bf(t[tx][ty + j * 8]);
}

// ---------- 2b. V transpose (FALLBACK only, when ws too small to fuse) ----------

__global__ __launch_bounds__(256) void v_transpose(const ushort* __restrict__ qkv,
                                                   ushort* __restrict__ vt) {
  __shared__ ushort t[64][66];
  const int s0 = blockIdx.x * 64, h = blockIdx.y, b = blockIdx.z;
  const size_t tokbase = (size_t)b * SEQ;
  for (int e = 0; e < 2; ++e) {
    const int c = e * 256 + threadIdx.x;
    const int sr = c >> 3, dc = c & 7;
    *(uint4*)&t[sr][dc * 8] =
        *(const uint4*)(qkv + (tokbase + s0 + sr) * NQKV + 2 * HID + h * HDIM + dc * 8);
  }
  __syncthreads();
  for (int e = 0; e < 2; ++e) {
    const int c = e * 256 + threadIdx.x;
    const int dr = c >> 3, sc = c & 7;
    ushort tmp[8];
    for (int j = 0; j < 8; ++j) tmp[j] = t[sc * 8 + j][dr];
    *(uint4*)(vt + ((size_t)(b * NHEAD + h) * HDIM + dr) * SEQ + s0 + sc * 8) = *(uint4*)tmp;
  }
}

// ---------- 3. GEMM  C[M][N] = A[M][K] * Bt[N][K]^T  (bf16 in, fp32 acc) ----------
// Proven 128-sq structure + fused V-transpose epilogue (R6) + T1 XCD swizzle.
// R11: SWAPPED-OPERAND MFMA for non-V blocks — mfma(bfr, af, acc) transposes
// the C-fragment so per-thread reg r spans 4 CONSECUTIVE OUTPUT COLUMNS at a
// fixed token (flash's S^T trick, proven in-file). Epilogue then vectorizes:
//   MODE 0 Q/K: 64 f2bf + 64 scalar-2B stores -> 32 cvtpk + 16 x 8B stores
//   MODE 1:     64 scalar resid loads + 64 scalar f32 stores -> 16+16 float4
// V-region blocks (n0>=2*HID, fused-VT) keep unswapped MFMA (need r = rows
// for the s-contiguous vt store). Swap choice is block-uniform.

template <int MODE>
__global__ __launch_bounds__(256) void gemm_bt(const ushort* __restrict__ A,
                                               const ushort* __restrict__ Bt,
                                               const float* __restrict__ bias,
                                               const float* __restrict__ resid,
                                               ushort* __restrict__ obf,
                                               float* __restrict__ of32,
                                               ushort* __restrict__ vtob,
                                               int M, int N, int K) {
  __shared__ ushort As[128 * 64];
  __shared__ ushort Bs[128 * 64];
  const int tid = threadIdx.x;
  const int lane = tid & 63, wv = tid >> 6;
  const int q = lane >> 4, li = lane & 15;
  // T1 XCD swizzle: hw id -> logical tile, 8 contiguous chunks
  const int nwgx = gridDim.x;
  const int hw = blockIdx.x + nwgx * blockIdx.y;
  const int cpx = (nwgx * gridDim.y) >> 3;          // nwg/8 (nwg%8==0)
  const int logical = (hw & 7) * cpx + (hw >> 3);
  const int bx = logical % nwgx, by = logical / nwgx;
  const int m0 = by * 128, n0 = bx * 128;
  const int wm = (wv >> 1) * 64, wn = (wv & 1) * 64;
  // V-region blocks keep unswapped MFMA (r = consecutive tokens for vt store)
  const bool vblk = (MODE == 0 && vtob != nullptr && n0 >= 2 * HID);
  f32x4 acc[4][4] = {};

  for (int kb = 0; kb < K; kb += 64) {
    for (int e = 0; e < 4; ++e) {
      const int chunk = (wv * 4 + e) * 64 + lane;
      const int row = chunk >> 3, slot = chunk & 7;
      const int kc = slot ^ (row & 7);
      glds16(A  + (size_t)(m0 + row) * K + kb + kc * 8, As + (wv * 4 + e) * 512);
      glds16(Bt + (size_t)(n0 + row) * K + kb + kc * 8, Bs + (wv * 4 + e) * 512);
    }
    __syncthreads();
    for (int ks = 0; ks < 2; ++ks) {
      const int kc = ks * 4 + q;
      bf16x8 af[4], bfr[4];
      for (int mi = 0; mi < 4; ++mi) {
        const int row = wm + mi * 16 + li;
        af[mi] = *(const bf16x8*)(As + (row * 8 + (kc ^ (row & 7))) * 8);
      }
      for (int ni = 0; ni < 4; ++ni) {
        const int row = wn + ni * 16 + li;
        bfr[ni] = *(const bf16x8*)(Bs + (row * 8 + (kc ^ (row & 7))) * 8);
      }
      if (vblk) {
        for (int mi = 0; mi < 4; ++mi)
          for (int ni = 0; ni < 4; ++ni)
            acc[mi][ni] = __builtin_amdgcn_mfma_f32_16x16x32_bf16(af[mi], bfr[ni], acc[mi][ni], 0, 0, 0);
      } else {
        for (int mi = 0; mi < 4; ++mi)
          for (int ni = 0; ni < 4; ++ni)
            acc[mi][ni] = __builtin_amdgcn_mfma_f32_16x16x32_bf16(bfr[ni], af[mi], acc[mi][ni], 0, 0, 0);
      }
    }
    __syncthreads();
  }

  if (vblk) {
    // fused V-transpose epilogue (unswapped acc: r = consecutive tokens):
    // vt[b][h][d][s], s contiguous in r
    const int b = (m0 + wm) >> 11;            // SEQ=2048 rows per batch
    const int sbase = (m0 + wm) & (SEQ - 1);  // + mi*16 + q*4
    for (int ni = 0; ni < 4; ++ni) {
      const int colv = n0 - 2 * HID + wn + ni * 16 + li;
      const int h = colv >> 6, d = colv & 63;
      const float bvs = bias[n0 + wn + ni * 16 + li];
      ushort* vbase = vtob + ((size_t)(b * NHEAD + h) * HDIM + d) * SEQ;
      for (int mi = 0; mi < 4; ++mi) {
        const int s = sbase + mi * 16 + q * 4;
        ushort4 o;
        o.x = f2bf(acc[mi][ni][0] + bvs);
        o.y = f2bf(acc[mi][ni][1] + bvs);
        o.z = f2bf(acc[mi][ni][2] + bvs);
        o.w = f2bf(acc[mi][ni][3] + bvs);
        *(ushort4*)(vbase + s) = o;
      }
    }
    return;
  }

  // swapped epilogue: tok = m0+wm+mi*16+li ; cols n0+wn+ni*16+q*4+{0..3}
  const float qs = (MODE == 0 && n0 < HID) ? QSCALE : 1.0f;
  for (int mi = 0; mi < 4; ++mi) {
    const size_t tok = (size_t)(m0 + wm + mi * 16 + li);
    for (int ni = 0; ni < 4; ++ni) {
      const int colb = n0 + wn + ni * 16 + q * 4;
      const float4 b4 = *(const float4*)(bias + colb);
      const float v0 = fmaf(acc[mi][ni][0], qs, b4.x * qs);
      const float v1 = fmaf(acc[mi][ni][1], qs, b4.y * qs);
      const float v2 = fmaf(acc[mi][ni][2], qs, b4.z * qs);
      const float v3 = fmaf(acc[mi][ni][3], qs, b4.w * qs);
      if (MODE == 0) {
        uint2 o;
        o.x = cvtpk(v0, v1);
        o.y = cvtpk(v2, v3);
        *(uint2*)(obf + tok * N + colb) = o;
      } else {
        const float4 r4 = *(const float4*)(resid + tok * N + colb);
        float4 o;
        o.x = v0 + r4.x; o.y = v1 + r4.y; o.z = v2 + r4.z; o.w = v3 + r4.w;
        *(float4*)(of32 + tok * N + colb) = o;
      }
    }
  }
}

// ---------- 4. flash attention (R13 winner + PRE mask table; frozen) ----------

template <int PRE>
__global__ __launch_bounds__(512) void flash_attn(const ushort* __restrict__ qkv,
                                                  const ushort* __restrict__ vt,
                                                  const float* __restrict__ mask,
                                                  ushort* __restrict__ outa) {
  __shared__ ushort KV[2][8192];   // per buf: [0..4095]=K (sigma rows), [4096..8191]=V^T
  const int tid = threadIdx.x, lane = tid & 63, wv = tid >> 6;   // wv 0..7
  const int quad = lane >> 4, li = lane & 15;
  const int wq = wv * 32;          // staged q-row base (0..224 over 256 rows)
  constexpr int NT = SEQ / 64;     // 32 kv tiles

  // XCD-aware remap: 8 qt-pair blocks of one (b,h) share an XCD
  const int L = blockIdx.x + 8 * blockIdx.y + 128 * blockIdx.z;  // 0..511
  const int xcd = L & 7, rrem = L >> 3;     // rrem 0..63
  const int p = (rrem >> 3) * 8 + xcd;      // (b,h) group 0..63
  const int qt0 = rrem & 7, h = p & 15, b = p >> 4;

  const size_t tokbase = (size_t)b * SEQ;
  const size_t vtbase = (size_t)(b * NHEAD + h) * HDIM * SEQ;
  const float* mrow = mask + (size_t)b * SEQ;

  // ---- prologue: stage BOTH Q tiles (256 rows = 32KB = whole KV) ----
  for (int e = 0; e < 4; ++e) {
    const int c = (wv * 4 + e) * 64 + lane;   // 0..2047
    const int row = c >> 3, slot = c & 7;     // staged row 0..255
    const int kc = slot ^ (row & 7);
    const int gtok = qt0 * 128 + (row & 127) + (row >> 7) * 1024;  // tileB = qt0+8
    glds16(qkv + (tokbase + gtok) * NQKV + h * HDIM + kc * 8,
           &KV[0][0] + (wv * 4 + e) * 512);
  }
  __syncthreads();  // Q landed

  // hoist Q fragments to registers (loop-invariant; per-wave rows)
  bf16x8 qf[2][2];
  for (int ks = 0; ks < 2; ++ks) {
    const int kc = ks * 4 + quad;
    for (int nq = 0; nq < 2; ++nq) {
      const int row = wq + nq * 16 + li;
      qf[ks][nq] = *(const bf16x8*)(&KV[0][0] + (row * 8 + (kc ^ (row & 7))) * 8);
    }
  }
  __syncthreads();  // all Q reads done; KV may be overwritten

  // hoisted LDS fragment offsets (ushort elements), loop-invariant
  int koff[2][4], voff[2][4];
  for (int ks = 0; ks < 2; ++ks) {
    const int kc = ks * 4 + quad;
    for (int i = 0; i < 4; ++i) {
      const int row = i * 16 + li;
      koff[ks][i] = (row * 8 + (kc ^ (row & 7))) * 8;
      voff[ks][i] = koff[ks][i] + 4096;   // V^T shares the row pattern, +8KB
    }
  }
  // per-lane staging offsets (u32, saddr form); 1 K-unit + 1 V-unit per wave
  unsigned ksoff, vsoff;
  {
    const int c = wv * 64 + lane;         // 0..511
    const int row = c >> 3, slot = c & 7; // kv row 0..63
    const int kc = slot ^ (row & 7);
    const int gkv = (row & 0x23) | ((row & 0x0c) << 1) | ((row & 0x10) >> 2);
    ksoff = (unsigned)((tokbase + gkv) * NQKV + HID + h * HDIM + kc * 8);
    vsoff = (unsigned)(vtbase + (size_t)row * SEQ + kc * 8);
  }

  const unsigned int one2 = 0x3F803F80u;  // bf16 1.0 x2
  bf16x8 ones;
  for (int j = 0; j < 4; ++j) ((unsigned int*)&ones)[j] = one2;

  f32x4 accO[2][4] = {};
  f32x4 accL[2] = {};   // l per q-row, accO C-layout (all 16 n-cols identical)

  auto stage_kv = [&](int t, int buf) {
    const unsigned ka = (unsigned)(t * (64 * NQKV));
    const unsigned va = (unsigned)(t * 64);
    glds16(qkv + ksoff + ka, &KV[buf][0] + wv * 512);
    glds16(vt + vsoff + va,  &KV[buf][4096] + wv * 512);
  };

  // mask prefetch: tile t's mask*LOG2E (PRE=1: table is pre-scaled, pure loads)
  auto mask_fetch = [&](int t, f32x4 (&mk)[4]) {
    const int kv0 = (t & (NT - 1)) * 64;   // wrap on the final (unused) prefetch
    for (int m = 0; m < 4; ++m) {
      if (PRE) {
        mk[m] = *(const f32x4*)(mrow + kv0 + (m >> 1) * 32 + quad * 8 + (m & 1) * 4);
      } else {
        const float4 v = *(const float4*)(mrow + kv0 + (m >> 1) * 32 + quad * 8 + (m & 1) * 4);
        mk[m][0] = v.x * LOG2E; mk[m][1] = v.y * LOG2E;
        mk[m][2] = v.z * LOG2E; mk[m][3] = v.w * LOG2E;
      }
    }
  };

  auto compute = [&](int t, int buf, f32x4 (&mkc)[4], f32x4 (&mkn)[4]) {
    mask_fetch(t + 1, mkn);

    const ushort* Kb = &KV[buf][0];

    // logits^T = K * Q^T + mask*LOG2E (C-init) — one setprio MFMA cluster
    f32x4 sc[2][4];
    __builtin_amdgcn_s_setprio(1);
    for (int ks = 0; ks < 2; ++ks) {
      bf16x8 kf[4];
      for (int m = 0; m < 4; ++m)
        kf[m] = *(const bf16x8*)(Kb + koff[ks][m]);
      for (int nq = 0; nq < 2; ++nq)
        for (int m = 0; m < 4; ++m)
          sc[nq][m] = __builtin_amdgcn_mfma_f32_16x16x32_bf16(
              kf[m], qf[ks][nq], ks == 0 ? mkc[m] : sc[nq][m], 0, 0, 0);
    }
    __builtin_amdgcn_s_setprio(0);

    // ks-split: softmax kv-rows [32ks,32ks+32) then PV slice ks.
    for (int ks = 0; ks < 2; ++ks) {
      bf16x8 vf[4];
      for (int nd = 0; nd < 4; ++nd)
        vf[nd] = *(const bf16x8*)(Kb + voff[ks][nd]);   // latency hides under exp2
      unsigned int pk[2][2][2];
      for (int nq = 0; nq < 2; ++nq)
        for (int mm = 0; mm < 2; ++mm) {
          const int m = 2 * ks + mm;
          const float p0 = __builtin_amdgcn_exp2f(sc[nq][m][0]);
          const float p1 = __builtin_amdgcn_exp2f(sc[nq][m][1]);
          const float p2 = __builtin_amdgcn_exp2f(sc[nq][m][2]);
          const float p3 = __builtin_amdgcn_exp2f(sc[nq][m][3]);
          pk[nq][mm][0] = cvtpk(p0, p1);
          pk[nq][mm][1] = cvtpk(p2, p3);
        }
      __builtin_amdgcn_s_setprio(1);
      for (int mq = 0; mq < 2; ++mq) {
        bf16x8 pf;
        ((unsigned int*)&pf)[0] = pk[mq][0][0];
        ((unsigned int*)&pf)[1] = pk[mq][0][1];
        ((unsigned int*)&pf)[2] = pk[mq][1][0];
        ((unsigned int*)&pf)[3] = pk[mq][1][1];
        for (int nd = 0; nd < 4; ++nd)
          accO[mq][nd] = __builtin_amdgcn_mfma_f32_16x16x32_bf16(pf, vf[nd], accO[mq][nd], 0, 0, 0);
        accL[mq] = __builtin_amdgcn_mfma_f32_16x16x32_bf16(pf, ones, accL[mq], 0, 0, 0);
      }
      __builtin_amdgcn_s_setprio(0);
    }
  };

  // ---- main loop: double-buffered, 1 barrier per tile ----
  f32x4 mkA[4], mkB[4];
  mask_fetch(0, mkA);
  stage_kv(0, 0);
  for (int t = 0; t < NT; t += 2) {  // static mkA/mkB swap (rule #20)
    __syncthreads();              // pf(t)->buf0 landed; reads of buf1 done
    stage_kv(t + 1, 1);
    compute(t, 0, mkA, mkB);
    __syncthreads();              // pf(t+1)->buf1 landed; reads of buf0 done
    if (t + 2 < SEQ / 64) stage_kv(t + 2, 0);
    compute(t + 1, 1, mkB, mkA);
  }

  // epilogue: normalize by l (already in accO layout — no shuffles), store bf16
  for (int mq = 0; mq < 2; ++mq)
    for (int r = 0; r < 4; ++r) {
      const float inv = 1.0f / accL[mq][r];
      const size_t tok = tokbase + qt0 * 128 + ((size_t)(wv >> 2) << 10) +
                         (wv & 3) * 32 + mq * 16 + quad * 4 + r;
      for (int nd = 0; nd < 4; ++nd)
        outa[tok * HID + h * HDIM + nd * 16 + li] = f2bf(accO[mq][nd][r] * inv);
    }
}

// ---------- launch ----------

extern "C" void kernel_launch(void* const* d_in, const int* in_sizes, int n_in,
                              void* d_out, int out_size, void* d_ws, size_t ws_size,
                              hipStream_t stream) {
  const float* hidden = (const float*)d_in[0];
  const float* mask   = (const float*)d_in[1];
  const float* gamma  = (const float*)d_in[2];
  const float* beta   = (const float*)d_in[3];
  const float* Wqkv   = (const float*)d_in[4];
  const float* bqkv   = (const float*)d_in[5];
  const float* Wout   = (const float*)d_in[6];
  const float* bout   = (const float*)d_in[7];
  float* out = (float*)d_out;

  char* ws = (char*)d_ws;
  // fused-VT layout needs vt NOT aliasing x_bf (gemm0 reads x_bf while
  // writing vt — cross-block race if aliased). Guard on ws_size.
  const bool fuse_vt = ws_size >= ((size_t)104 << 20);
  const bool pre_msk = ws_size >= (((size_t)104 << 20) + (NB * SEQ * 4 + 65536));
  ushort* x_bf  = (ushort*)(ws);                       // 16 MB
  ushort* wqkvT = (ushort*)(ws + ((size_t)16 << 20));  //  6 MB
  ushort* woutT = (ushort*)(ws + ((size_t)22 << 20));  //  2 MB
  ushort* qkvb  = (ushort*)(ws + ((size_t)24 << 20));  // 48 MB (V third unused when fused)
  ushort* attnb = (ushort*)(ws + ((size_t)72 << 20));  // 16 MB
  ushort* vtb   = fuse_vt ? (ushort*)(ws + ((size_t)88 << 20))  // 16 MB
                          : (ushort*)(ws);             // fallback: alias x_bf (dead after gemm0)
  float* m2     = pre_msk ? (float*)(ws + ((size_t)104 << 20)) : nullptr;  // 32 KB

  ln_tr_fused<<<NTOK + 4096 + (m2 ? 8 : 0), 256, 0, stream>>>(
      hidden, gamma, beta, x_bf, Wqkv, wqkvT, Wout, woutT, mask, m2);
  gemm_bt<0><<<dim3(NQKV / 128, NTOK / 128), 256, 0, stream>>>(
      x_bf, wqkvT, bqkv, nullptr, qkvb, nullptr, fuse_vt ? vtb : nullptr, NTOK, NQKV, HID);
  if (!fuse_vt)
    v_transpose<<<dim3(SEQ / 64, NHEAD, NB), 256, 0, stream>>>(qkvb, vtb);
  if (m2)
    flash_attn<1><<<dim3(SEQ / 256, NHEAD, NB), 512, 0, stream>>>(qkvb, vtb, m2, attnb);
  else
    flash_attn<0><<<dim3(SEQ / 256, NHEAD, NB), 512, 0, stream>>>(qkvb, vtb, mask, attnb);
  gemm_bt<1><<<dim3(HID / 128, NTOK / 128), 256, 0, stream>>>(
      attnb, woutT, bout, hidden, nullptr, out, nullptr, NTOK, HID, HID);
}

// Round 12
// 279.900 us; speedup vs baseline: 1.2701x; 1.2701x over previous
//
#include <hip/hip_runtime.h>

#define SEQ 2048
#define HID 1024
#define NHEAD 16
#define HDIM 64
#define NB 4
#define NTOK (NB * SEQ)   // 8192
#define NQKV (3 * HID)    // 3072
#define LOG2E 1.44269504088896f
#define QSCALE (0.125f * LOG2E)   // folded into gemm0's Q-column epilogue

typedef __attribute__((ext_vector_type(8))) short bf16x8;
typedef __attribute__((ext_vector_type(4))) float f32x4;

// ---------- helpers ----------

__device__ __forceinline__ void glds16(const void* g, void* l) {
  // async global->LDS, 16B per lane; LDS dest = wave-uniform base + lane*16
  __builtin_amdgcn_global_load_lds(
      (const __attribute__((address_space(1))) void*)g,
      (__attribute__((address_space(3))) void*)l, 16, 0, 0);
}

__device__ __forceinline__ ushort f2bf(float f) {
  union { float f; unsigned int u; } a; a.f = f;
  unsigned int u = a.u;
  return (ushort)((u + 0x7fffu + ((u >> 16) & 1u)) >> 16);  // RNE
}

// pack two fp32 -> bf16x2 in ONE VALU op (RNE). T12 primitive; validated R1/R2.
__device__ __forceinline__ unsigned int cvtpk(float a, float b) {
  unsigned int r;
  asm("v_cvt_pk_bf16_f32 %0, %1, %2" : "=v"(r) : "v"(a), "v"(b));
  return r;  // lo = bf16(a), hi = bf16(b)
}

// ---------- 1. fused LayerNorm + weight-transpose + mask prescale ----------

__global__ __launch_bounds__(256) void ln_tr_fused(const float* __restrict__ x,
                                                   const float* __restrict__ g,
                                                   const float* __restrict__ be,
                                                   ushort* __restrict__ y,
                                                   const float* __restrict__ W0,
                                                   ushort* __restrict__ T0,
                                                   const float* __restrict__ W1,
                                                   ushort* __restrict__ T1,
                                                   const float* __restrict__ mask,
                                                   float* __restrict__ m2) {
  __shared__ float t[32][33];
  const int tid = threadIdx.x;
  if (blockIdx.x < NTOK) {
    const int row = blockIdx.x;
    const float4 v = ((const float4*)(x + (size_t)row * HID))[tid];
    float s  = v.x + v.y + v.z + v.w;
    float sq = v.x * v.x + v.y * v.y + v.z * v.z + v.w * v.w;
    for (int o = 1; o < 64; o <<= 1) { s += __shfl_xor(s, o, 64); sq += __shfl_xor(sq, o, 64); }
    const int wv = tid >> 6;
    if ((tid & 63) == 0) { t[0][wv] = s; t[1][wv] = sq; }
    __syncthreads();
    s  = t[0][0] + t[0][1] + t[0][2] + t[0][3];
    sq = t[1][0] + t[1][1] + t[1][2] + t[1][3];
    const float mu  = s * (1.0f / HID);
    const float var = sq * (1.0f / HID) - mu * mu;
    const float rs  = rsqrtf(var + 1e-12f);
    const float4 gv = ((const float4*)g)[tid];
    const float4 bv = ((const float4*)be)[tid];
    ushort4 o;
    o.x = f2bf((v.x - mu) * rs * gv.x + bv.x);
    o.y = f2bf((v.y - mu) * rs * gv.y + bv.y);
    o.z = f2bf((v.z - mu) * rs * gv.z + bv.z);
    o.w = f2bf((v.w - mu) * rs * gv.w + bv.w);
    ((ushort4*)(y + (size_t)row * HID))[tid] = o;
    return;
  }
  const int bid = blockIdx.x - NTOK;   // 0..4103
  if (bid >= 4096) {
    // mask prescale: 8 blocks x 1024 floats = NB*SEQ
    const int i = (bid - 4096) * 1024 + tid * 4;
    float4 v = *(const float4*)(mask + i);
    v.x *= LOG2E; v.y *= LOG2E; v.z *= LOG2E; v.w *= LOG2E;
    *(float4*)(m2 + i) = v;
    return;
  }
  // ---- transpose part ----
  const float* W; ushort* WT; int C, bx, by;
  if (bid < 3072) { W = W0; WT = T0; C = NQKV; bx = bid % 96; by = bid / 96; }
  else { const int b2 = bid - 3072; W = W1; WT = T1; C = HID; bx = b2 & 31; by = b2 >> 5; }
  const int R = HID;
  const int c0 = bx * 32, r0 = by * 32;
  const int tx = tid & 31, ty = tid >> 5;
  for (int j = 0; j < 4; ++j)
    t[ty + j * 8][tx] = W[(size_t)(r0 + ty + j * 8) * C + c0 + tx];
  __syncthreads();
  for (int j = 0; j < 4; ++j)
    WT[(size_t)(c0 + ty + j * 8) * R + r0 + tx] = f2bf(t[tx][ty + j * 8]);
}

// ---------- 2b. V transpose (FALLBACK only, when ws too small to fuse) ----------

__global__ __launch_bounds__(256) void v_transpose(const ushort* __restrict__ qkv,
                                                   ushort* __restrict__ vt) {
  __shared__ ushort t[64][66];
  const int s0 = blockIdx.x * 64, h = blockIdx.y, b = blockIdx.z;
  const size_t tokbase = (size_t)b * SEQ;
  for (int e = 0; e < 2; ++e) {
    const int c = e * 256 + threadIdx.x;
    const int sr = c >> 3, dc = c & 7;
    *(uint4*)&t[sr][dc * 8] =
        *(const uint4*)(qkv + (tokbase + s0 + sr) * NQKV + 2 * HID + h * HDIM + dc * 8);
  }
  __syncthreads();
  for (int e = 0; e < 2; ++e) {
    const int c = e * 256 + threadIdx.x;
    const int dr = c >> 3, sc = c & 7;
    ushort tmp[8];
    for (int j = 0; j < 8; ++j) tmp[j] = t[sc * 8 + j][dr];
    *(uint4*)(vt + ((size_t)(b * NHEAD + h) * HDIM + dr) * SEQ + s0 + sc * 8) = *(uint4*)tmp;
  }
}

// ---------- 3. GEMM  C[M][N] = A[M][K] * Bt[N][K]^T  (bf16 in, fp32 acc) ----------
// R12: REVERT to the R10-proven kernel verbatim. R11's swapped-operand
// epilogue made lane index -> token (stride 6144B): 64 cache lines per store
// instruction, RFO fetch amplification 25->160MB, gemm0 151us. Lesson:
// coalescing is inter-LANE contiguity; the old epilogue's 16-lane x 2B = 32B
// segments (4 ni-stores completing each 128B line) was already WC-friendly.
// Structure: proven 128-sq + fused V-transpose (R6) + T1 XCD swizzle (R8).

template <int MODE>
__global__ __launch_bounds__(256) void gemm_bt(const ushort* __restrict__ A,
                                               const ushort* __restrict__ Bt,
                                               const float* __restrict__ bias,
                                               const float* __restrict__ resid,
                                               ushort* __restrict__ obf,
                                               float* __restrict__ of32,
                                               ushort* __restrict__ vtob,
                                               int M, int N, int K) {
  __shared__ ushort As[128 * 64];
  __shared__ ushort Bs[128 * 64];
  const int tid = threadIdx.x;
  const int lane = tid & 63, wv = tid >> 6;
  const int q = lane >> 4, li = lane & 15;
  // T1 XCD swizzle: hw id -> logical tile, 8 contiguous chunks
  const int nwgx = gridDim.x;
  const int hw = blockIdx.x + nwgx * blockIdx.y;
  const int cpx = (nwgx * gridDim.y) >> 3;          // nwg/8 (nwg%8==0)
  const int logical = (hw & 7) * cpx + (hw >> 3);
  const int bx = logical % nwgx, by = logical / nwgx;
  const int m0 = by * 128, n0 = bx * 128;
  const int wm = (wv >> 1) * 64, wn = (wv & 1) * 64;
  f32x4 acc[4][4] = {};

  for (int kb = 0; kb < K; kb += 64) {
    for (int e = 0; e < 4; ++e) {
      const int chunk = (wv * 4 + e) * 64 + lane;
      const int row = chunk >> 3, slot = chunk & 7;
      const int kc = slot ^ (row & 7);
      glds16(A  + (size_t)(m0 + row) * K + kb + kc * 8, As + (wv * 4 + e) * 512);
      glds16(Bt + (size_t)(n0 + row) * K + kb + kc * 8, Bs + (wv * 4 + e) * 512);
    }
    __syncthreads();
    for (int ks = 0; ks < 2; ++ks) {
      const int kc = ks * 4 + q;
      bf16x8 af[4], bfr[4];
      for (int mi = 0; mi < 4; ++mi) {
        const int row = wm + mi * 16 + li;
        af[mi] = *(const bf16x8*)(As + (row * 8 + (kc ^ (row & 7))) * 8);
      }
      for (int ni = 0; ni < 4; ++ni) {
        const int row = wn + ni * 16 + li;
        bfr[ni] = *(const bf16x8*)(Bs + (row * 8 + (kc ^ (row & 7))) * 8);
      }
      for (int mi = 0; mi < 4; ++mi)
        for (int ni = 0; ni < 4; ++ni)
          acc[mi][ni] = __builtin_amdgcn_mfma_f32_16x16x32_bf16(af[mi], bfr[ni], acc[mi][ni], 0, 0, 0);
    }
    __syncthreads();
  }

  if (MODE == 0 && vtob != nullptr && n0 >= 2 * HID) {
    // fused V-transpose epilogue: vt[b][h][d][s], s contiguous in r
    const int b = (m0 + wm) >> 11;            // SEQ=2048 rows per batch
    const int sbase = (m0 + wm) & (SEQ - 1);  // + mi*16 + q*4
    for (int ni = 0; ni < 4; ++ni) {
      const int colv = n0 - 2 * HID + wn + ni * 16 + li;
      const int h = colv >> 6, d = colv & 63;
      const float bvs = bias[n0 + wn + ni * 16 + li];
      ushort* vbase = vtob + ((size_t)(b * NHEAD + h) * HDIM + d) * SEQ;
      for (int mi = 0; mi < 4; ++mi) {
        const int s = sbase + mi * 16 + q * 4;
        ushort4 o;
        o.x = f2bf(acc[mi][ni][0] + bvs);
        o.y = f2bf(acc[mi][ni][1] + bvs);
        o.z = f2bf(acc[mi][ni][2] + bvs);
        o.w = f2bf(acc[mi][ni][3] + bvs);
        *(ushort4*)(vbase + s) = o;
      }
    }
    return;
  }

  const float qs = (MODE == 0 && n0 < HID) ? QSCALE : 1.0f;
  for (int ni = 0; ni < 4; ++ni) {
    const int col = n0 + wn + ni * 16 + li;
    const float bvs = bias[col] * qs;
    for (int mi = 0; mi < 4; ++mi) {
      for (int r = 0; r < 4; ++r) {
        const int row = m0 + wm + mi * 16 + q * 4 + r;
        const float v = fmaf(acc[mi][ni][r], qs, bvs);
        if (MODE == 0) obf[(size_t)row * N + col] = f2bf(v);
        else           of32[(size_t)row * N + col] = v + resid[(size_t)row * N + col];
      }
    }
  }
}

// ---------- 4. flash attention (R13 winner + PRE mask table; frozen) ----------

template <int PRE>
__global__ __launch_bounds__(512) void flash_attn(const ushort* __restrict__ qkv,
                                                  const ushort* __restrict__ vt,
                                                  const float* __restrict__ mask,
                                                  ushort* __restrict__ outa) {
  __shared__ ushort KV[2][8192];   // per buf: [0..4095]=K (sigma rows), [4096..8191]=V^T
  const int tid = threadIdx.x, lane = tid & 63, wv = tid >> 6;   // wv 0..7
  const int quad = lane >> 4, li = lane & 15;
  const int wq = wv * 32;          // staged q-row base (0..224 over 256 rows)
  constexpr int NT = SEQ / 64;     // 32 kv tiles

  // XCD-aware remap: 8 qt-pair blocks of one (b,h) share an XCD
  const int L = blockIdx.x + 8 * blockIdx.y + 128 * blockIdx.z;  // 0..511
  const int xcd = L & 7, rrem = L >> 3;     // rrem 0..63
  const int p = (rrem >> 3) * 8 + xcd;      // (b,h) group 0..63
  const int qt0 = rrem & 7, h = p & 15, b = p >> 4;

  const size_t tokbase = (size_t)b * SEQ;
  const size_t vtbase = (size_t)(b * NHEAD + h) * HDIM * SEQ;
  const float* mrow = mask + (size_t)b * SEQ;

  // ---- prologue: stage BOTH Q tiles (256 rows = 32KB = whole KV) ----
  for (int e = 0; e < 4; ++e) {
    const int c = (wv * 4 + e) * 64 + lane;   // 0..2047
    const int row = c >> 3, slot = c & 7;     // staged row 0..255
    const int kc = slot ^ (row & 7);
    const int gtok = qt0 * 128 + (row & 127) + (row >> 7) * 1024;  // tileB = qt0+8
    glds16(qkv + (tokbase + gtok) * NQKV + h * HDIM + kc * 8,
           &KV[0][0] + (wv * 4 + e) * 512);
  }
  __syncthreads();  // Q landed

  // hoist Q fragments to registers (loop-invariant; per-wave rows)
  bf16x8 qf[2][2];
  for (int ks = 0; ks < 2; ++ks) {
    const int kc = ks * 4 + quad;
    for (int nq = 0; nq < 2; ++nq) {
      const int row = wq + nq * 16 + li;
      qf[ks][nq] = *(const bf16x8*)(&KV[0][0] + (row * 8 + (kc ^ (row & 7))) * 8);
    }
  }
  __syncthreads();  // all Q reads done; KV may be overwritten

  // hoisted LDS fragment offsets (ushort elements), loop-invariant
  int koff[2][4], voff[2][4];
  for (int ks = 0; ks < 2; ++ks) {
    const int kc = ks * 4 + quad;
    for (int i = 0; i < 4; ++i) {
      const int row = i * 16 + li;
      koff[ks][i] = (row * 8 + (kc ^ (row & 7))) * 8;
      voff[ks][i] = koff[ks][i] + 4096;   // V^T shares the row pattern, +8KB
    }
  }
  // per-lane staging offsets (u32, saddr form); 1 K-unit + 1 V-unit per wave
  unsigned ksoff, vsoff;
  {
    const int c = wv * 64 + lane;         // 0..511
    const int row = c >> 3, slot = c & 7; // kv row 0..63
    const int kc = slot ^ (row & 7);
    const int gkv = (row & 0x23) | ((row & 0x0c) << 1) | ((row & 0x10) >> 2);
    ksoff = (unsigned)((tokbase + gkv) * NQKV + HID + h * HDIM + kc * 8);
    vsoff = (unsigned)(vtbase + (size_t)row * SEQ + kc * 8);
  }

  const unsigned int one2 = 0x3F803F80u;  // bf16 1.0 x2
  bf16x8 ones;
  for (int j = 0; j < 4; ++j) ((unsigned int*)&ones)[j] = one2;

  f32x4 accO[2][4] = {};
  f32x4 accL[2] = {};   // l per q-row, accO C-layout (all 16 n-cols identical)

  auto stage_kv = [&](int t, int buf) {
    const unsigned ka = (unsigned)(t * (64 * NQKV));
    const unsigned va = (unsigned)(t * 64);
    glds16(qkv + ksoff + ka, &KV[buf][0] + wv * 512);
    glds16(vt + vsoff + va,  &KV[buf][4096] + wv * 512);
  };

  // mask prefetch: tile t's mask*LOG2E (PRE=1: table is pre-scaled, pure loads)
  auto mask_fetch = [&](int t, f32x4 (&mk)[4]) {
    const int kv0 = (t & (NT - 1)) * 64;   // wrap on the final (unused) prefetch
    for (int m = 0; m < 4; ++m) {
      if (PRE) {
        mk[m] = *(const f32x4*)(mrow + kv0 + (m >> 1) * 32 + quad * 8 + (m & 1) * 4);
      } else {
        const float4 v = *(const float4*)(mrow + kv0 + (m >> 1) * 32 + quad * 8 + (m & 1) * 4);
        mk[m][0] = v.x * LOG2E; mk[m][1] = v.y * LOG2E;
        mk[m][2] = v.z * LOG2E; mk[m][3] = v.w * LOG2E;
      }
    }
  };

  auto compute = [&](int t, int buf, f32x4 (&mkc)[4], f32x4 (&mkn)[4]) {
    mask_fetch(t + 1, mkn);

    const ushort* Kb = &KV[buf][0];

    // logits^T = K * Q^T + mask*LOG2E (C-init) — one setprio MFMA cluster
    f32x4 sc[2][4];
    __builtin_amdgcn_s_setprio(1);
    for (int ks = 0; ks < 2; ++ks) {
      bf16x8 kf[4];
      for (int m = 0; m < 4; ++m)
        kf[m] = *(const bf16x8*)(Kb + koff[ks][m]);
      for (int nq = 0; nq < 2; ++nq)
        for (int m = 0; m < 4; ++m)
          sc[nq][m] = __builtin_amdgcn_mfma_f32_16x16x32_bf16(
              kf[m], qf[ks][nq], ks == 0 ? mkc[m] : sc[nq][m], 0, 0, 0);
    }
    __builtin_amdgcn_s_setprio(0);

    // ks-split: softmax kv-rows [32ks,32ks+32) then PV slice ks.
    for (int ks = 0; ks < 2; ++ks) {
      bf16x8 vf[4];
      for (int nd = 0; nd < 4; ++nd)
        vf[nd] = *(const bf16x8*)(Kb + voff[ks][nd]);   // latency hides under exp2
      unsigned int pk[2][2][2];
      for (int nq = 0; nq < 2; ++nq)
        for (int mm = 0; mm < 2; ++mm) {
          const int m = 2 * ks + mm;
          const float p0 = __builtin_amdgcn_exp2f(sc[nq][m][0]);
          const float p1 = __builtin_amdgcn_exp2f(sc[nq][m][1]);
          const float p2 = __builtin_amdgcn_exp2f(sc[nq][m][2]);
          const float p3 = __builtin_amdgcn_exp2f(sc[nq][m][3]);
          pk[nq][mm][0] = cvtpk(p0, p1);
          pk[nq][mm][1] = cvtpk(p2, p3);
        }
      __builtin_amdgcn_s_setprio(1);
      for (int mq = 0; mq < 2; ++mq) {
        bf16x8 pf;
        ((unsigned int*)&pf)[0] = pk[mq][0][0];
        ((unsigned int*)&pf)[1] = pk[mq][0][1];
        ((unsigned int*)&pf)[2] = pk[mq][1][0];
        ((unsigned int*)&pf)[3] = pk[mq][1][1];
        for (int nd = 0; nd < 4; ++nd)
          accO[mq][nd] = __builtin_amdgcn_mfma_f32_16x16x32_bf16(pf, vf[nd], accO[mq][nd], 0, 0, 0);
        accL[mq] = __builtin_amdgcn_mfma_f32_16x16x32_bf16(pf, ones, accL[mq], 0, 0, 0);
      }
      __builtin_amdgcn_s_setprio(0);
    }
  };

  // ---- main loop: double-buffered, 1 barrier per tile ----
  f32x4 mkA[4], mkB[4];
  mask_fetch(0, mkA);
  stage_kv(0, 0);
  for (int t = 0; t < NT; t += 2) {  // static mkA/mkB swap (rule #20)
    __syncthreads();              // pf(t)->buf0 landed; reads of buf1 done
    stage_kv(t + 1, 1);
    compute(t, 0, mkA, mkB);
    __syncthreads();              // pf(t+1)->buf1 landed; reads of buf0 done
    if (t + 2 < SEQ / 64) stage_kv(t + 2, 0);
    compute(t + 1, 1, mkB, mkA);
  }

  // epilogue: normalize by l (already in accO layout — no shuffles), store bf16
  for (int mq = 0; mq < 2; ++mq)
    for (int r = 0; r < 4; ++r) {
      const float inv = 1.0f / accL[mq][r];
      const size_t tok = tokbase + qt0 * 128 + ((size_t)(wv >> 2) << 10) +
                         (wv & 3) * 32 + mq * 16 + quad * 4 + r;
      for (int nd = 0; nd < 4; ++nd)
        outa[tok * HID + h * HDIM + nd * 16 + li] = f2bf(accO[mq][nd][r] * inv);
    }
}

// ---------- launch ----------

extern "C" void kernel_launch(void* const* d_in, const int* in_sizes, int n_in,
                              void* d_out, int out_size, void* d_ws, size_t ws_size,
                              hipStream_t stream) {
  const float* hidden = (const float*)d_in[0];
  const float* mask   = (const float*)d_in[1];
  const float* gamma  = (const float*)d_in[2];
  const float* beta   = (const float*)d_in[3];
  const float* Wqkv   = (const float*)d_in[4];
  const float* bqkv   = (const float*)d_in[5];
  const float* Wout   = (const float*)d_in[6];
  const float* bout   = (const float*)d_in[7];
  float* out = (float*)d_out;

  char* ws = (char*)d_ws;
  // fused-VT layout needs vt NOT aliasing x_bf (gemm0 reads x_bf while
  // writing vt — cross-block race if aliased). Guard on ws_size.
  const bool fuse_vt = ws_size >= ((size_t)104 << 20);
  const bool pre_msk = ws_size >= (((size_t)104 << 20) + (NB * SEQ * 4 + 65536));
  ushort* x_bf  = (ushort*)(ws);                       // 16 MB
  ushort* wqkvT = (ushort*)(ws + ((size_t)16 << 20));  //  6 MB
  ushort* woutT = (ushort*)(ws + ((size_t)22 << 20));  //  2 MB
  ushort* qkvb  = (ushort*)(ws + ((size_t)24 << 20));  // 48 MB (V third unused when fused)
  ushort* attnb = (ushort*)(ws + ((size_t)72 << 20));  // 16 MB
  ushort* vtb   = fuse_vt ? (ushort*)(ws + ((size_t)88 << 20))  // 16 MB
                          : (ushort*)(ws);             // fallback: alias x_bf (dead after gemm0)
  float* m2     = pre_msk ? (float*)(ws + ((size_t)104 << 20)) : nullptr;  // 32 KB

  ln_tr_fused<<<NTOK + 4096 + (m2 ? 8 : 0), 256, 0, stream>>>(
      hidden, gamma, beta, x_bf, Wqkv, wqkvT, Wout, woutT, mask, m2);
  gemm_bt<0><<<dim3(NQKV / 128, NTOK / 128), 256, 0, stream>>>(
      x_bf, wqkvT, bqkv, nullptr, qkvb, nullptr, fuse_vt ? vtb : nullptr, NTOK, NQKV, HID);
  if (!fuse_vt)
    v_transpose<<<dim3(SEQ / 64, NHEAD, NB), 256, 0, stream>>>(qkvb, vtb);
  if (m2)
    flash_attn<1><<<dim3(SEQ / 256, NHEAD, NB), 512, 0, stream>>>(qkvb, vtb, m2, attnb);
  else
    flash_attn<0><<<dim3(SEQ / 256, NHEAD, NB), 512, 0, stream>>>(qkvb, vtb, mask, attnb);
  gemm_bt<1><<<dim3(HID / 128, NTOK / 128), 256, 0, stream>>>(
      attnb, woutT, bout, hidden, nullptr, out, nullptr, NTOK, HID, HID);
}